// Round 9
// baseline (250.357 us; speedup 1.0000x reference)
//
#include <hip/hip_runtime.h>
#include <hip/hip_bf16.h>

// ---------------------------------------------------------------------------
// QLSTM fused pipelined: seq=256, batch=512, input=256, H=n_qubits=8.
// ONE kernel, 256 blocks x 512 threads. Block b owns batches {2b, 2b+1}.
// Producer-consumer pipeline over 4 chunks of 64 timesteps (R6 structure):
//   wave 0     : scans chunk k-1 (BOTH batches as TWO independent register
//                chains, interleaved instruction streams -> ILP=2 on the
//                serial dependency chain)
//   waves 1-4  : MFMA-gemm chunk k (128 local rows) into the other buffer
//   waves 5-7  : idle at barriers
// R9 = R8 + dual-chain scan. Chain A = batch 2b (state in all 64 lanes),
// chain B = batch 2b+1. History/final writes select by lane's bl.
// Per-chain arithmetic identical to R8 (verified, absmax 0.0078125).
// ---------------------------------------------------------------------------

#define SEQ   256
#define BATCH 512
#define DIN   256
#define NROWS (SEQ * BATCH)      // 131072
#define DCOMB 264                // 256 + 8
#define CHT   64                 // timesteps per chunk
#define NCH   (SEQ / CHT)        // 4 chunks
#define ZBSTR 130                // floats per (bl,q) stream in a chunk buffer
#define ZBUFSZ (32 * ZBSTR + 16) // +16 pad: last body's harmless over-prefetch
#define HLSTR 260                // floats per c-row of history: 256 + 4 pad
#define INV2PI 0.15915494309189535f

typedef __attribute__((ext_vector_type(8))) short short8;
typedef __attribute__((ext_vector_type(4))) float f32x4;
typedef __attribute__((ext_vector_type(2))) float f32x2;

__device__ __forceinline__ short f2bf(float f) {
    union { __hip_bfloat16 h; short s; } u;
    u.h = __float2bfloat16(f);
    return u.s;
}
__device__ __forceinline__ float bf2f(short s) {
    union { short s; __hip_bfloat16 h; } u;
    u.s = s;
    return __bfloat162float(u.h);
}

__device__ __forceinline__ short8 pack8(float4 a, float4 b) {
    union { short8 s8; int i[4]; } u;
    union { __hip_bfloat162 h; int i; } v;
    v.h = __float22bfloat162_rn(make_float2(a.x, a.y)); u.i[0] = v.i;
    v.h = __float22bfloat162_rn(make_float2(a.z, a.w)); u.i[1] = v.i;
    v.h = __float22bfloat162_rn(make_float2(b.x, b.y)); u.i[2] = v.i;
    v.h = __float22bfloat162_rn(make_float2(b.z, b.w)); u.i[3] = v.i;
    return u.s8;
}

// DPP conventions (verified): row_shr:d -> dst[i]=src[i-d], invalid -> old;
// row_ror:s -> dst[i]=src[(i-s) mod 16]; quad_perm ctrl in [0,0xFF].
#define DPP_ROR(V, S) \
    __int_as_float(__builtin_amdgcn_update_dpp(__float_as_int(V), __float_as_int(V), 0x120 | (S), 0xF, 0xF, false))
#define QP(V, CTRL) \
    __int_as_float(__builtin_amdgcn_update_dpp(__float_as_int(V), __float_as_int(V), (CTRL), 0xF, 0xF, false))
// prefix-product stage, shift D lanes (= D/2 qubits); shifted-in value = 1.0
#define PSTG2(A, D) { \
    float s0_ = __int_as_float(__builtin_amdgcn_update_dpp(one_i, __float_as_int(A.x), 0x110 | (D), 0xF, 0xF, false)); \
    float s1_ = __int_as_float(__builtin_amdgcn_update_dpp(one_i, __float_as_int(A.y), 0x110 | (D), 0xF, 0xF, false)); \
    A *= (f32x2){s0_, s1_}; }

// one scan step for ONE chain: z2 -> updates hx, cx; returns new hx.
// z and wp arrive pre-scaled by 1/(2pi): p is in revolutions -> raw v_cos.
__device__ __forceinline__ float scan_step(
    const f32x2 z2, float& hx, float& cx,
    const f32x2 (&wp)[8], const f32x2 cth,
    const f32x2 k0, const f32x2 k1, const f32x2 k2, const f32x2 k3,
    const f32x2 k4, const int one_i)
{
    // hx rotations (hx pair-duplicated; qubit shift s = lane ror 2s)
    const float h0 = hx;
    const float h1 = DPP_ROR(hx, 2),  h2 = DPP_ROR(hx, 4);
    const float h3 = DPP_ROR(hx, 6),  h4 = DPP_ROR(hx, 8);
    const float h5 = DPP_ROR(hx, 10), h6 = DPP_ROR(hx, 12);
    const float h7 = DPP_ROR(hx, 14);

    // pre-pair (in revolutions) = z + hx @ Wh'.T (balanced fma tree)
    f32x2 e0 = (f32x2){h0, h0} * wp[0] + (f32x2){h1, h1} * wp[1];
    f32x2 e1 = (f32x2){h2, h2} * wp[2] + (f32x2){h3, h3} * wp[3];
    f32x2 e2 = (f32x2){h4, h4} * wp[4] + (f32x2){h5, h5} * wp[5];
    f32x2 e3 = (f32x2){h6, h6} * wp[6] + (f32x2){h7, h7} * wp[7];
    const f32x2 p = ((z2 + e0) + (e1 + e2)) + e3;

    // qgate: a = cos(2pi*p)*cos(theta) via raw v_cos, then prefix product
    f32x2 A = (f32x2){__builtin_amdgcn_cosf(p.x),
                      __builtin_amdgcn_cosf(p.y)} * cth;
    PSTG2(A, 2) PSTG2(A, 4) PSTG2(A, 8)

    // activations via per-lane poly, Estrin (|A|<=1)
    const f32x2 t2 = A * A;
    const f32x2 t4 = t2 * t2;
    const f32x2 ra = k1 + t2 * k2;
    const f32x2 rb = k3 + t2 * k4;
    const f32x2 P  = k0 + A * (ra + t4 * rb);

    // broadcast all 4 gates to both lanes of the pair (quad_perm)
    const float f_all = QP(P.x, 0xA0);   // [0,0,2,2]
    const float u_all = QP(P.x, 0xF5);   // [1,1,3,3]
    const float i_all = QP(P.y, 0xA0);
    const float o_all = QP(P.y, 0xF5);

    // cx = f*cx + i*u   (valid in ALL lanes, pair-duplicated)
    cx = fmaf(f_all, cx, i_all * u_all);

    // tanh(cx) via Pade[5/4] (|cx| <= ~2.1), 1 rcp
    const float tq  = cx * cx;
    const float num = cx * fmaf(tq, fmaf(tq, 1.0f, 105.0f), 945.0f);
    const float den = fmaf(tq, fmaf(tq, 15.0f, 420.0f), 945.0f);
    hx = o_all * (num * __builtin_amdgcn_rcpf(den));
    return hx;
}

// one 8-step DUAL-chain scan body: chains A and B advance together, their
// independent instruction streams interleaved for ILP. Consumes ZCa/ZCb,
// prefetches ZNa/ZNb (last body over-prefetches into pad, never consumed),
// flushes history (per-lane bl selects which chain this lane records).
__device__ __forceinline__ void scan_body8_dual(
    int T0L, int T0G,
    const float* __restrict__ zrowA, const float* __restrict__ zrowB,
    float* __restrict__ hlrow, bool writer, int bl,
    f32x4 (&ZCa)[4], f32x4 (&ZNa)[4], f32x4 (&ZCb)[4], f32x4 (&ZNb)[4],
    float& hxA, float& cxA, float& hxB, float& cxB,
    const f32x2 (&wp)[8], const f32x2 cth,
    const f32x2 k0, const f32x2 k1, const f32x2 k2, const f32x2 k3,
    const f32x2 k4, const int one_i)
{
    #pragma unroll
    for (int j = 0; j < 4; ++j) {
        ZNa[j] = *(const f32x4*)&zrowA[(T0L + 8) * 2 + j * 4];
        ZNb[j] = *(const f32x4*)&zrowB[(T0L + 8) * 2 + j * 4];
    }

    float ha[8], hb[8];
    #pragma unroll
    for (int u = 0; u < 8; ++u) {
        const f32x2 z2a = (f32x2){ ZCa[u >> 1][(u & 1) * 2],
                                   ZCa[u >> 1][(u & 1) * 2 + 1] };
        const f32x2 z2b = (f32x2){ ZCb[u >> 1][(u & 1) * 2],
                                   ZCb[u >> 1][(u & 1) * 2 + 1] };
        ha[u] = scan_step(z2a, hxA, cxA, wp, cth, k0, k1, k2, k3, k4, one_i);
        hb[u] = scan_step(z2b, hxB, cxB, wp, cth, k0, k1, k2, k3, k4, one_i);
    }

    if (writer) {
        const f32x4 v0 = bl ? (f32x4){hb[0], hb[1], hb[2], hb[3]}
                            : (f32x4){ha[0], ha[1], ha[2], ha[3]};
        const f32x4 v1 = bl ? (f32x4){hb[4], hb[5], hb[6], hb[7]}
                            : (f32x4){ha[4], ha[5], ha[6], ha[7]};
        *(f32x4*)&hlrow[T0G]     = v0;
        *(f32x4*)&hlrow[T0G + 4] = v1;
    }
}

__global__ __launch_bounds__(512, 1) void qlstm_fused(
    const float* __restrict__ X,
    const float* __restrict__ Wf, const float* __restrict__ Wi,
    const float* __restrict__ Wu, const float* __restrict__ Wo,
    const float* __restrict__ bfv, const float* __restrict__ biv,
    const float* __restrict__ buv, const float* __restrict__ bov,
    const float* __restrict__ pf, const float* __restrict__ pi_,
    const float* __restrict__ pu, const float* __restrict__ po,
    float* __restrict__ out)
{
    // [nt(2)][hl(2)][ks(8)][lane(64)] bf16 B-fragments: 2048 * 16 B = 32 KB
    __shared__ short8 Wl[2048];
    // double-buffered Z chunk ring: [2][stream 0..31][t_local*2+comp]. 33 KB
    __shared__ float Zb[2][ZBUFSZ];
    // hx history: [c = bl*8+kq][t], stride 260. 16.25 KB
    __shared__ float Hl2[16 * HLSTR];

    const int tx  = threadIdx.x;
    const int l   = tx & 63;
    const int wid = tx >> 6;
    const int lm  = l & 15;
    const int lk  = l >> 4;
    const int B0  = blockIdx.x;              // batch pair index

    const float* Wg[4] = {Wf, Wi, Wu, Wo};
    const float* Bg[4] = {bfv, biv, buv, bov};

    // ---- preamble: W*(1/2pi) -> LDS bf16 hi/lo fragments (once per block) --
    #pragma unroll
    for (int e = 0; e < 4; ++e) {
        const int ent  = tx + e * 512;       // 0..2047
        const int lane = ent & 63;
        const int ks   = (ent >> 6) & 7;
        const int hl   = (ent >> 9) & 1;
        const int nt   = (ent >> 10) & 1;
        const int elm  = lane & 15, elk = lane >> 4;
        const int c    = nt * 16 + elm;      // col = kq*4 + g
        const float* wrow = Wg[c & 3] + (c >> 2) * DCOMB + ks * 32 + elk * 8;
        short8 fr;
        #pragma unroll
        for (int j = 0; j < 8; ++j) {
            const float v = wrow[j] * INV2PI;
            const short h16 = f2bf(v);
            fr[j] = hl ? f2bf(v - bf2f(h16)) : h16;
        }
        Wl[ent] = fr;
    }

    // bias per lane (bias of output col = lane's D column), pre-scaled
    float bias0, bias1;
    { const int c0 = lm;      bias0 = Bg[c0 & 3][c0 >> 2] * INV2PI;
      const int c1 = 16 + lm; bias1 = Bg[c1 & 3][c1 >> 2] * INV2PI; }

    // ---- scanner state (wave 0 lanes only; cheap to set up) ----------------
    const int q   = tx & 15;                 // lane-in-batch 0..15
    const int kq  = q >> 1;                  // qubit index
    const int hi  = q & 1;                   // 0: gates (f,i); 1: (u,o)
    const int bl  = (tx >> 4) & 1;           // writer's batch-in-pair select
    const int woff = kq * DCOMB + DIN;

    f32x2 wp[8];
    f32x2 cth = (f32x2){1.0f, 1.0f};
    if (wid == 0) {
        const float* WgA = hi ? Wu : Wf;
        const float* WgB = hi ? Wo : Wi;
        #pragma unroll
        for (int s = 0; s < 8; ++s) {
            const int j = (kq - s) & 7;
            wp[s] = (f32x2){WgA[woff + j] * INV2PI, WgB[woff + j] * INV2PI};
        }
        cth = (f32x2){__cosf((hi ? pu : pf)[kq]),
                      __cosf((hi ? po : pi_)[kq])};
    }
    // activation poly: act(x) = k0 + x*(k1 + t2*k2 + t4*(k3 + t2*k4)), t2=x^2
    const float SK1 = 0.25f, SK2 = -0.0208333333f, SK3 = 0.0020833333f,
                SK4 = -0.00021082f;
    const f32x2 k0 = (f32x2){hi ? 0.0f : 0.5f, 0.5f};
    const f32x2 k1 = (f32x2){hi ? 0.9999016f : SK1, SK1};
    const f32x2 k2 = (f32x2){hi ? -0.3310485f : SK2, SK2};
    const f32x2 k3 = (f32x2){hi ? 0.1204423f : SK3, SK3};
    const f32x2 k4 = (f32x2){hi ? -0.0277012f : SK4, SK4};
    const int one_i = __float_as_int(1.0f);

    // chain A = batch 2*B0 (stream rows 0..15), chain B = 2*B0+1 (16..31);
    // both chains' state lives in ALL 64 lanes (per-lane q mapping).
    float hxA = 0.0f, cxA = 0.0f, hxB = 0.0f, cxB = 0.0f;
    const float* __restrict__ zrAbase = &Zb[0][q * ZBSTR];
    const float* __restrict__ zrBbase = &Zb[0][(16 + q) * ZBSTR];
    float* __restrict__ hlrow = &Hl2[(bl * 8 + kq) * HLSTR];
    const bool writer = (hi == 0) && (tx < 32);
    f32x4 rAa[4], rBa[4], rAb[4], rBb[4];

    __syncthreads();

    // ---- pipeline: 5 iterations; produce chunk k || scan chunk k-1 ---------
    #pragma unroll 1
    for (int k = 0; k <= NCH; ++k) {
        if (wid == 0) {
            if (k >= 1) {
                // scan chunk k-1 (64 steps, both chains) from Zb[(k-1)&1]
                const float* __restrict__ zA = zrAbase + ((k - 1) & 1) * ZBUFSZ;
                const float* __restrict__ zB = zrBbase + ((k - 1) & 1) * ZBUFSZ;
                const int TG = (k - 1) * CHT;
                #pragma unroll
                for (int j = 0; j < 4; ++j) {
                    rAa[j] = *(const f32x4*)&zA[j * 4];
                    rAb[j] = *(const f32x4*)&zB[j * 4];
                }
                scan_body8_dual( 0, TG,      zA, zB, hlrow, writer, bl, rAa, rBa, rAb, rBb, hxA, cxA, hxB, cxB, wp, cth, k0, k1, k2, k3, k4, one_i);
                scan_body8_dual( 8, TG + 8,  zA, zB, hlrow, writer, bl, rBa, rAa, rBb, rAb, hxA, cxA, hxB, cxB, wp, cth, k0, k1, k2, k3, k4, one_i);
                scan_body8_dual(16, TG + 16, zA, zB, hlrow, writer, bl, rAa, rBa, rAb, rBb, hxA, cxA, hxB, cxB, wp, cth, k0, k1, k2, k3, k4, one_i);
                scan_body8_dual(24, TG + 24, zA, zB, hlrow, writer, bl, rBa, rAa, rBb, rAb, hxA, cxA, hxB, cxB, wp, cth, k0, k1, k2, k3, k4, one_i);
                scan_body8_dual(32, TG + 32, zA, zB, hlrow, writer, bl, rAa, rBa, rAb, rBb, hxA, cxA, hxB, cxB, wp, cth, k0, k1, k2, k3, k4, one_i);
                scan_body8_dual(40, TG + 40, zA, zB, hlrow, writer, bl, rBa, rAa, rBb, rAb, hxA, cxA, hxB, cxB, wp, cth, k0, k1, k2, k3, k4, one_i);
                scan_body8_dual(48, TG + 48, zA, zB, hlrow, writer, bl, rAa, rBa, rAb, rBb, hxA, cxA, hxB, cxB, wp, cth, k0, k1, k2, k3, k4, one_i);
                scan_body8_dual(56, TG + 56, zA, zB, hlrow, writer, bl, rBa, rAa, rBb, rAb, hxA, cxA, hxB, cxB, wp, cth, k0, k1, k2, k3, k4, one_i);
                if (k == NCH && writer) {
                    const int oidx = (B0 * 2 + bl) * 8 + kq;
                    out[NROWS * 8 + oidx]        = bl ? hxB : hxA;  // final hx
                    out[NROWS * 8 + 4096 + oidx] = bl ? cxB : cxA;  // final cx
                }
            }
        } else if (wid <= 4 && k < NCH) {
            // produce chunk k (128 local rows) into Zb[k&1]
            float* __restrict__ bufp = &Zb[k & 1][0];
            #pragma unroll
            for (int g = 0; g < 2; ++g) {
                const int r0 = k * 128 + (wid - 1) * 32 + g * 16;
                const int r  = r0 + lm;      // this lane's A-row (= 2t+bl local)
                const float* xbase =
                    X + ((long)(r >> 1) * BATCH + B0 * 2 + (r & 1)) * DIN + lk * 8;

                float4 xv[16];
                #pragma unroll
                for (int i = 0; i < 16; ++i)
                    xv[i] = *(const float4*)(xbase + (i >> 1) * 32 + (i & 1) * 4);

                f32x4 acc0 = (f32x4){bias0, bias0, bias0, bias0};
                f32x4 acc1 = (f32x4){bias1, bias1, bias1, bias1};
                #pragma unroll
                for (int ks = 0; ks < 8; ++ks) {
                    const short8 a = pack8(xv[2 * ks], xv[2 * ks + 1]);
                    acc0 = __builtin_amdgcn_mfma_f32_16x16x32_bf16(a, Wl[ks * 64 + l],        acc0, 0, 0, 0);
                    acc0 = __builtin_amdgcn_mfma_f32_16x16x32_bf16(a, Wl[(8  + ks) * 64 + l], acc0, 0, 0, 0);
                    acc1 = __builtin_amdgcn_mfma_f32_16x16x32_bf16(a, Wl[(16 + ks) * 64 + l], acc1, 0, 0, 0);
                    acc1 = __builtin_amdgcn_mfma_f32_16x16x32_bf16(a, Wl[(24 + ks) * 64 + l], acc1, 0, 0, 0);
                }

                // D layout: col = lane&15, row = (lane>>4)*4 + reg.
                // (local r, col c) -> stream (r&1)*16 + (c>>1), idx tl*2+(c&1)
                #pragma unroll
                for (int rr = 0; rr < 4; ++rr) {
                    const int rw   = r0 + lk * 4 + rr;
                    const int tl   = (rw - k * 128) >> 1;
                    const int blw  = rw & 1;
                    bufp[(blw * 16 + (lm >> 1)) * ZBSTR + tl * 2 + (lm & 1)]     = acc0[rr];
                    bufp[(blw * 16 + 8 + (lm >> 1)) * ZBSTR + tl * 2 + (lm & 1)] = acc1[rr];
                }
            }
        }
        __syncthreads();
    }

    // ---- epilogue: gather-transpose dump of hx history (all 8 waves) -------
    {
        const int f0 = tx * 8;               // 0..4095
        const int t  = f0 >> 4;              // 0..255
        const int c0 = f0 & 15;              // 0 or 8
        float4 v0, v1;
        v0.x = Hl2[(c0 + 0) * HLSTR + t];
        v0.y = Hl2[(c0 + 1) * HLSTR + t];
        v0.z = Hl2[(c0 + 2) * HLSTR + t];
        v0.w = Hl2[(c0 + 3) * HLSTR + t];
        v1.x = Hl2[(c0 + 4) * HLSTR + t];
        v1.y = Hl2[(c0 + 5) * HLSTR + t];
        v1.z = Hl2[(c0 + 6) * HLSTR + t];
        v1.w = Hl2[(c0 + 7) * HLSTR + t];
        float4* dst = (float4*)(out + (long)t * (BATCH * 8) + B0 * 16 + c0);
        dst[0] = v0;
        dst[1] = v1;
    }
}

// ---------------------------------------------------------------------------
extern "C" void kernel_launch(void* const* d_in, const int* in_sizes, int n_in,
                              void* d_out, int out_size, void* d_ws, size_t ws_size,
                              hipStream_t stream) {
    const float* X   = (const float*)d_in[0];
    const float* Wf  = (const float*)d_in[1];
    const float* bfv = (const float*)d_in[2];
    const float* Wi  = (const float*)d_in[3];
    const float* biv = (const float*)d_in[4];
    const float* Wu  = (const float*)d_in[5];
    const float* buv = (const float*)d_in[6];
    const float* Wo  = (const float*)d_in[7];
    const float* bov = (const float*)d_in[8];
    const float* pf  = (const float*)d_in[9];
    const float* pi_ = (const float*)d_in[10];
    const float* pu  = (const float*)d_in[11];
    const float* po  = (const float*)d_in[12];
    float* out = (float*)d_out;
    (void)d_ws; (void)ws_size;               // workspace not needed

    qlstm_fused<<<BATCH / 2, 512, 0, stream>>>(
        X, Wf, Wi, Wu, Wo, bfv, biv, buv, bov, pf, pi_, pu, po, out);
}

// Round 10
// 223.035 us; speedup vs baseline: 1.1225x; 1.1225x over previous
//
#include <hip/hip_runtime.h>
#include <hip/hip_bf16.h>

// ---------------------------------------------------------------------------
// QLSTM fused pipelined: seq=256, batch=512, input=256, H=n_qubits=8.
// ONE kernel, 256 blocks x 512 threads. Block b owns batches {2b, 2b+1}.
// Producer-consumer pipeline over 4 chunks of 64 timesteps (R6 structure):
//   wave 0     : scans chunk k-1 from LDS ring buffer (256-step recurrence)
//   waves 1-4  : MFMA-gemm chunk k (128 local rows) into the other buffer
//   waves 5-7  : idle at barriers
// R10 = exact R6 (best verified: 220.3) + s_setprio(1) around the scan body
// (wave 0 shares SIMD0 with producer wave 4; the scan is issue-bound at
// ~2.2 cy/instr, so producer issue slots stolen on SIMD0 add directly to
// the serial chain — setprio gives the scan wave arbitration priority).
// Scan math identical to R1..R6 (verified, absmax 0.0078125).
// ---------------------------------------------------------------------------

#define SEQ   256
#define BATCH 512
#define DIN   256
#define NROWS (SEQ * BATCH)      // 131072
#define DCOMB 264                // 256 + 8
#define CHT   64                 // timesteps per chunk
#define NCH   (SEQ / CHT)        // 4 chunks
#define ZBSTR 130                // floats per (bl,q) stream in a chunk buffer
#define ZBUFSZ (32 * ZBSTR + 16) // +16 pad: last body's harmless over-prefetch
#define HLSTR 260                // floats per c-row of history: 256 + 4 pad

typedef __attribute__((ext_vector_type(8))) short short8;
typedef __attribute__((ext_vector_type(4))) float f32x4;
typedef __attribute__((ext_vector_type(2))) float f32x2;

__device__ __forceinline__ short f2bf(float f) {
    union { __hip_bfloat16 h; short s; } u;
    u.h = __float2bfloat16(f);
    return u.s;
}
__device__ __forceinline__ float bf2f(short s) {
    union { short s; __hip_bfloat16 h; } u;
    u.s = s;
    return __bfloat162float(u.h);
}

__device__ __forceinline__ short8 pack8(float4 a, float4 b) {
    union { short8 s8; int i[4]; } u;
    union { __hip_bfloat162 h; int i; } v;
    v.h = __float22bfloat162_rn(make_float2(a.x, a.y)); u.i[0] = v.i;
    v.h = __float22bfloat162_rn(make_float2(a.z, a.w)); u.i[1] = v.i;
    v.h = __float22bfloat162_rn(make_float2(b.x, b.y)); u.i[2] = v.i;
    v.h = __float22bfloat162_rn(make_float2(b.z, b.w)); u.i[3] = v.i;
    return u.s8;
}

// DPP conventions (verified): row_shr:d -> dst[i]=src[i-d], invalid -> old;
// row_ror:s -> dst[i]=src[(i-s) mod 16]; quad_perm ctrl in [0,0xFF].
#define DPP_ROR(V, S) \
    __int_as_float(__builtin_amdgcn_update_dpp(__float_as_int(V), __float_as_int(V), 0x120 | (S), 0xF, 0xF, false))
#define QP(V, CTRL) \
    __int_as_float(__builtin_amdgcn_update_dpp(__float_as_int(V), __float_as_int(V), (CTRL), 0xF, 0xF, false))
// prefix-product stage, shift D lanes (= D/2 qubits); shifted-in value = 1.0
#define PSTG2(A, D) { \
    float s0_ = __int_as_float(__builtin_amdgcn_update_dpp(one_i, __float_as_int(A.x), 0x110 | (D), 0xF, 0xF, false)); \
    float s1_ = __int_as_float(__builtin_amdgcn_update_dpp(one_i, __float_as_int(A.y), 0x110 | (D), 0xF, 0xF, false)); \
    A *= (f32x2){s0_, s1_}; }

// one 8-step scan body: consume ZC (local chunk offset T0L), prefetch ZN
// (T0L+8; last body over-prefetches into pad, never consumed), flush hx
// history for global steps T0G..T0G+7. Indices static after inlining.
__device__ __forceinline__ void scan_body8(
    int T0L, int T0G, const float* __restrict__ zrow,
    float* __restrict__ hlrow, bool writer,
    f32x4 (&ZC)[4], f32x4 (&ZN)[4],
    float& hx, float& cx,
    const f32x2 (&wp)[8], const f32x2 cth,
    const f32x2 k0, const f32x2 k1, const f32x2 k2, const f32x2 k3,
    const f32x2 k4, const int one_i)
{
    #pragma unroll
    for (int j = 0; j < 4; ++j)
        ZN[j] = *(const f32x4*)&zrow[(T0L + 8) * 2 + j * 4];

    float hxh[8];
    #pragma unroll
    for (int u = 0; u < 8; ++u) {
        const f32x2 z2 = (f32x2){ ZC[u >> 1][(u & 1) * 2],
                                  ZC[u >> 1][(u & 1) * 2 + 1] };

        // hx rotations (hx pair-duplicated; qubit shift s = lane ror 2s)
        const float h0 = hx;
        const float h1 = DPP_ROR(hx, 2),  h2 = DPP_ROR(hx, 4);
        const float h3 = DPP_ROR(hx, 6),  h4 = DPP_ROR(hx, 8);
        const float h5 = DPP_ROR(hx, 10), h6 = DPP_ROR(hx, 12);
        const float h7 = DPP_ROR(hx, 14);

        // pre-pair = z + hx @ Wh.T (balanced fma tree)
        f32x2 e0 = (f32x2){h0, h0} * wp[0] + (f32x2){h1, h1} * wp[1];
        f32x2 e1 = (f32x2){h2, h2} * wp[2] + (f32x2){h3, h3} * wp[3];
        f32x2 e2 = (f32x2){h4, h4} * wp[4] + (f32x2){h5, h5} * wp[5];
        f32x2 e3 = (f32x2){h6, h6} * wp[6] + (f32x2){h7, h7} * wp[7];
        const f32x2 p = ((z2 + e0) + (e1 + e2)) + e3;

        // qgate: a = cos(pre)*cos(theta), then qubit prefix product
        f32x2 A = (f32x2){__cosf(p.x), __cosf(p.y)} * cth;
        PSTG2(A, 2) PSTG2(A, 4) PSTG2(A, 8)

        // activations via per-lane poly (|A|<=1)
        const f32x2 t2 = A * A;
        f32x2 rr = k3 + t2 * k4;
        rr = k2 + t2 * rr;
        rr = k1 + t2 * rr;
        const f32x2 P = k0 + A * rr;

        // broadcast all 4 gates to both lanes of the pair (quad_perm)
        const float f_all = QP(P.x, 0xA0);   // [0,0,2,2]
        const float u_all = QP(P.x, 0xF5);   // [1,1,3,3]
        const float i_all = QP(P.y, 0xA0);
        const float o_all = QP(P.y, 0xF5);

        // cx = f*cx + i*u   (valid in ALL lanes, pair-duplicated)
        cx = fmaf(f_all, cx, i_all * u_all);

        // tanh(cx) via Pade[5/4] (|cx| <= ~2.1), 1 rcp
        const float tq  = cx * cx;
        const float num = cx * fmaf(tq, fmaf(tq, 1.0f, 105.0f), 945.0f);
        const float den = fmaf(tq, fmaf(tq, 15.0f, 420.0f), 945.0f);
        const float tc  = num * __builtin_amdgcn_rcpf(den);

        // hx = o * tanh(cx) — valid in all lanes
        hx = o_all * tc;
        hxh[u] = hx;
    }

    if (writer) {
        *(f32x4*)&hlrow[T0G]     = (f32x4){hxh[0], hxh[1], hxh[2], hxh[3]};
        *(f32x4*)&hlrow[T0G + 4] = (f32x4){hxh[4], hxh[5], hxh[6], hxh[7]};
    }
}

__global__ __launch_bounds__(512, 1) void qlstm_fused(
    const float* __restrict__ X,
    const float* __restrict__ Wf, const float* __restrict__ Wi,
    const float* __restrict__ Wu, const float* __restrict__ Wo,
    const float* __restrict__ bfv, const float* __restrict__ biv,
    const float* __restrict__ buv, const float* __restrict__ bov,
    const float* __restrict__ pf, const float* __restrict__ pi_,
    const float* __restrict__ pu, const float* __restrict__ po,
    float* __restrict__ out)
{
    // [nt(2)][hl(2)][ks(8)][lane(64)] bf16 B-fragments: 2048 * 16 B = 32 KB
    __shared__ short8 Wl[2048];
    // double-buffered Z chunk ring: [2][stream 0..31][t_local*2+comp]. 33 KB
    __shared__ float Zb[2][ZBUFSZ];
    // hx history: [c = bl*8+kq][t], stride 260. 16.25 KB
    __shared__ float Hl2[16 * HLSTR];

    const int tx  = threadIdx.x;
    const int l   = tx & 63;
    const int wid = tx >> 6;
    const int lm  = l & 15;
    const int lk  = l >> 4;
    const int B0  = blockIdx.x;              // batch pair index

    const float* Wg[4] = {Wf, Wi, Wu, Wo};
    const float* Bg[4] = {bfv, biv, buv, bov};

    // ---- preamble: convert W -> LDS bf16 hi/lo fragments (once per block) ---
    #pragma unroll
    for (int e = 0; e < 4; ++e) {
        const int ent  = tx + e * 512;       // 0..2047
        const int lane = ent & 63;
        const int ks   = (ent >> 6) & 7;
        const int hl   = (ent >> 9) & 1;
        const int nt   = (ent >> 10) & 1;
        const int elm  = lane & 15, elk = lane >> 4;
        const int c    = nt * 16 + elm;      // col = kq*4 + g
        const float* wrow = Wg[c & 3] + (c >> 2) * DCOMB + ks * 32 + elk * 8;
        short8 fr;
        #pragma unroll
        for (int j = 0; j < 8; ++j) {
            const float v = wrow[j];
            const short h16 = f2bf(v);
            fr[j] = hl ? f2bf(v - bf2f(h16)) : h16;
        }
        Wl[ent] = fr;
    }

    // bias per lane (bias of output col = lane's D column) — producers use
    float bias0, bias1;
    { const int c0 = lm;      bias0 = Bg[c0 & 3][c0 >> 2];
      const int c1 = 16 + lm; bias1 = Bg[c1 & 3][c1 >> 2]; }

    // ---- scanner state (wave 0 lanes only; cheap to set up) ----------------
    const int q   = tx & 15;                 // lane-in-batch 0..15
    const int kq  = q >> 1;                  // qubit index
    const int hi  = q & 1;                   // 0: gates (f,i); 1: (u,o)
    const int bl  = (tx >> 4) & 1;           // batch-in-pair (mirrored 32-63)
    const int oidx = (B0 * 2 + bl) * 8 + kq;
    const int woff = kq * DCOMB + DIN;

    f32x2 wp[8];
    f32x2 cth = (f32x2){1.0f, 1.0f};
    if (wid == 0) {
        const float* WgA = hi ? Wu : Wf;
        const float* WgB = hi ? Wo : Wi;
        #pragma unroll
        for (int s = 0; s < 8; ++s) {
            const int j = (kq - s) & 7;
            wp[s] = (f32x2){WgA[woff + j], WgB[woff + j]};
        }
        cth = (f32x2){__cosf((hi ? pu : pf)[kq]),
                      __cosf((hi ? po : pi_)[kq])};
    }
    // activation poly: act(x) = k0 + x*(k1 + t*(k2 + t*(k3 + t*k4))), t=x^2
    const float SK1 = 0.25f, SK2 = -0.0208333333f, SK3 = 0.0020833333f,
                SK4 = -0.00021082f;
    const f32x2 k0 = (f32x2){hi ? 0.0f : 0.5f, 0.5f};
    const f32x2 k1 = (f32x2){hi ? 0.9999016f : SK1, SK1};
    const f32x2 k2 = (f32x2){hi ? -0.3310485f : SK2, SK2};
    const f32x2 k3 = (f32x2){hi ? 0.1204423f : SK3, SK3};
    const f32x2 k4 = (f32x2){hi ? -0.0277012f : SK4, SK4};
    const int one_i = __float_as_int(1.0f);

    float hx = 0.0f, cx = 0.0f;
    const float* __restrict__ zrowb = &Zb[0][(bl * 16 + q) * ZBSTR];
    float* __restrict__ hlrow = &Hl2[(bl * 8 + kq) * HLSTR];
    const bool writer = (hi == 0) && (tx < 32);
    f32x4 zbA[4], zbB[4];

    __syncthreads();

    // ---- pipeline: 5 iterations; produce chunk k || scan chunk k-1 ---------
    #pragma unroll 1
    for (int k = 0; k <= NCH; ++k) {
        if (wid == 0) {
            if (k >= 1) {
                // scan chunk k-1 (64 steps) from Zb[(k-1)&1]
                const float* __restrict__ zrow = zrowb + ((k - 1) & 1) * ZBUFSZ;
                const int TG = (k - 1) * CHT;
                #pragma unroll
                for (int j = 0; j < 4; ++j) zbA[j] = *(const f32x4*)&zrow[j * 4];
                __builtin_amdgcn_s_setprio(1);   // scan wave is the critical path
                scan_body8( 0, TG,      zrow, hlrow, writer, zbA, zbB, hx, cx, wp, cth, k0, k1, k2, k3, k4, one_i);
                scan_body8( 8, TG + 8,  zrow, hlrow, writer, zbB, zbA, hx, cx, wp, cth, k0, k1, k2, k3, k4, one_i);
                scan_body8(16, TG + 16, zrow, hlrow, writer, zbA, zbB, hx, cx, wp, cth, k0, k1, k2, k3, k4, one_i);
                scan_body8(24, TG + 24, zrow, hlrow, writer, zbB, zbA, hx, cx, wp, cth, k0, k1, k2, k3, k4, one_i);
                scan_body8(32, TG + 32, zrow, hlrow, writer, zbA, zbB, hx, cx, wp, cth, k0, k1, k2, k3, k4, one_i);
                scan_body8(40, TG + 40, zrow, hlrow, writer, zbB, zbA, hx, cx, wp, cth, k0, k1, k2, k3, k4, one_i);
                scan_body8(48, TG + 48, zrow, hlrow, writer, zbA, zbB, hx, cx, wp, cth, k0, k1, k2, k3, k4, one_i);
                scan_body8(56, TG + 56, zrow, hlrow, writer, zbB, zbA, hx, cx, wp, cth, k0, k1, k2, k3, k4, one_i);
                __builtin_amdgcn_s_setprio(0);
                if (k == NCH && writer) {
                    out[NROWS * 8 + oidx]        = hx;   // final hx (512,8)
                    out[NROWS * 8 + 4096 + oidx] = cx;   // final cx (512,8)
                }
            }
        } else if (wid <= 4 && k < NCH) {
            // produce chunk k (128 local rows) into Zb[k&1]
            float* __restrict__ bufp = &Zb[k & 1][0];
            #pragma unroll
            for (int g = 0; g < 2; ++g) {
                const int r0 = k * 128 + (wid - 1) * 32 + g * 16;
                const int r  = r0 + lm;      // this lane's A-row (= 2t+bl local)
                const float* xbase =
                    X + ((long)(r >> 1) * BATCH + B0 * 2 + (r & 1)) * DIN + lk * 8;

                float4 xv[16];
                #pragma unroll
                for (int i = 0; i < 16; ++i)
                    xv[i] = *(const float4*)(xbase + (i >> 1) * 32 + (i & 1) * 4);

                f32x4 acc0 = (f32x4){bias0, bias0, bias0, bias0};
                f32x4 acc1 = (f32x4){bias1, bias1, bias1, bias1};
                #pragma unroll
                for (int ks = 0; ks < 8; ++ks) {
                    const short8 a = pack8(xv[2 * ks], xv[2 * ks + 1]);
                    acc0 = __builtin_amdgcn_mfma_f32_16x16x32_bf16(a, Wl[ks * 64 + l],        acc0, 0, 0, 0);
                    acc0 = __builtin_amdgcn_mfma_f32_16x16x32_bf16(a, Wl[(8  + ks) * 64 + l], acc0, 0, 0, 0);
                    acc1 = __builtin_amdgcn_mfma_f32_16x16x32_bf16(a, Wl[(16 + ks) * 64 + l], acc1, 0, 0, 0);
                    acc1 = __builtin_amdgcn_mfma_f32_16x16x32_bf16(a, Wl[(24 + ks) * 64 + l], acc1, 0, 0, 0);
                }

                // D layout: col = lane&15, row = (lane>>4)*4 + reg.
                // (local r, col c) -> stream (r&1)*16 + (c>>1), idx tl*2+(c&1)
                #pragma unroll
                for (int rr = 0; rr < 4; ++rr) {
                    const int rw   = r0 + lk * 4 + rr;
                    const int tl   = (rw - k * 128) >> 1;
                    const int blw  = rw & 1;
                    bufp[(blw * 16 + (lm >> 1)) * ZBSTR + tl * 2 + (lm & 1)]     = acc0[rr];
                    bufp[(blw * 16 + 8 + (lm >> 1)) * ZBSTR + tl * 2 + (lm & 1)] = acc1[rr];
                }
            }
        }
        __syncthreads();
    }

    // ---- epilogue: gather-transpose dump of hx history (all 8 waves) -------
    {
        const int f0 = tx * 8;               // 0..4095
        const int t  = f0 >> 4;              // 0..255
        const int c0 = f0 & 15;              // 0 or 8
        float4 v0, v1;
        v0.x = Hl2[(c0 + 0) * HLSTR + t];
        v0.y = Hl2[(c0 + 1) * HLSTR + t];
        v0.z = Hl2[(c0 + 2) * HLSTR + t];
        v0.w = Hl2[(c0 + 3) * HLSTR + t];
        v1.x = Hl2[(c0 + 4) * HLSTR + t];
        v1.y = Hl2[(c0 + 5) * HLSTR + t];
        v1.z = Hl2[(c0 + 6) * HLSTR + t];
        v1.w = Hl2[(c0 + 7) * HLSTR + t];
        float4* dst = (float4*)(out + (long)t * (BATCH * 8) + B0 * 16 + c0);
        dst[0] = v0;
        dst[1] = v1;
    }
}

// ---------------------------------------------------------------------------
extern "C" void kernel_launch(void* const* d_in, const int* in_sizes, int n_in,
                              void* d_out, int out_size, void* d_ws, size_t ws_size,
                              hipStream_t stream) {
    const float* X   = (const float*)d_in[0];
    const float* Wf  = (const float*)d_in[1];
    const float* bfv = (const float*)d_in[2];
    const float* Wi  = (const float*)d_in[3];
    const float* biv = (const float*)d_in[4];
    const float* Wu  = (const float*)d_in[5];
    const float* buv = (const float*)d_in[6];
    const float* Wo  = (const float*)d_in[7];
    const float* bov = (const float*)d_in[8];
    const float* pf  = (const float*)d_in[9];
    const float* pi_ = (const float*)d_in[10];
    const float* pu  = (const float*)d_in[11];
    const float* po  = (const float*)d_in[12];
    float* out = (float*)d_out;
    (void)d_ws; (void)ws_size;               // workspace not needed

    qlstm_fused<<<BATCH / 2, 512, 0, stream>>>(
        X, Wf, Wi, Wu, Wo, bfv, biv, buv, bov, pf, pi_, pu, po, out);
}

// Round 11
// 221.817 us; speedup vs baseline: 1.1287x; 1.0055x over previous
//
#include <hip/hip_runtime.h>
#include <hip/hip_bf16.h>

// ---------------------------------------------------------------------------
// QLSTM fused pipelined: seq=256, batch=512, input=256, H=n_qubits=8.
// ONE kernel, 256 blocks x 512 threads. Block b owns batches {2b, 2b+1}.
// Producer-consumer pipeline over 4 chunks of 64 timesteps (R6 structure):
//   wave 0           : scans chunk k-1 from LDS ring buffer (serial chain)
//   waves 1,2,3,5    : MFMA-gemm chunk k (128 local rows) into other buffer
//   waves 4,6,7      : idle at barriers
// R11 = exact R6 (best verified: 220.3) with producers remapped off SIMD0:
// wid&3 = SIMD index, so the old producer wave 4 shared SIMD0 with the
// issue-bound scan wave and stole issue slots. Slots {1,2,3,5} leave SIMD0
// to the scan alone (idle wave 4 at s_barrier consumes no issue).
// Scan math identical to R1..R6 (verified, absmax 0.0078125).
// ---------------------------------------------------------------------------

#define SEQ   256
#define BATCH 512
#define DIN   256
#define NROWS (SEQ * BATCH)      // 131072
#define DCOMB 264                // 256 + 8
#define CHT   64                 // timesteps per chunk
#define NCH   (SEQ / CHT)        // 4 chunks
#define ZBSTR 130                // floats per (bl,q) stream in a chunk buffer
#define ZBUFSZ (32 * ZBSTR + 16) // +16 pad: last body's harmless over-prefetch
#define HLSTR 260                // floats per c-row of history: 256 + 4 pad

typedef __attribute__((ext_vector_type(8))) short short8;
typedef __attribute__((ext_vector_type(4))) float f32x4;
typedef __attribute__((ext_vector_type(2))) float f32x2;

__device__ __forceinline__ short f2bf(float f) {
    union { __hip_bfloat16 h; short s; } u;
    u.h = __float2bfloat16(f);
    return u.s;
}
__device__ __forceinline__ float bf2f(short s) {
    union { short s; __hip_bfloat16 h; } u;
    u.s = s;
    return __bfloat162float(u.h);
}

__device__ __forceinline__ short8 pack8(float4 a, float4 b) {
    union { short8 s8; int i[4]; } u;
    union { __hip_bfloat162 h; int i; } v;
    v.h = __float22bfloat162_rn(make_float2(a.x, a.y)); u.i[0] = v.i;
    v.h = __float22bfloat162_rn(make_float2(a.z, a.w)); u.i[1] = v.i;
    v.h = __float22bfloat162_rn(make_float2(b.x, b.y)); u.i[2] = v.i;
    v.h = __float22bfloat162_rn(make_float2(b.z, b.w)); u.i[3] = v.i;
    return u.s8;
}

// DPP conventions (verified): row_shr:d -> dst[i]=src[i-d], invalid -> old;
// row_ror:s -> dst[i]=src[(i-s) mod 16]; quad_perm ctrl in [0,0xFF].
#define DPP_ROR(V, S) \
    __int_as_float(__builtin_amdgcn_update_dpp(__float_as_int(V), __float_as_int(V), 0x120 | (S), 0xF, 0xF, false))
#define QP(V, CTRL) \
    __int_as_float(__builtin_amdgcn_update_dpp(__float_as_int(V), __float_as_int(V), (CTRL), 0xF, 0xF, false))
// prefix-product stage, shift D lanes (= D/2 qubits); shifted-in value = 1.0
#define PSTG2(A, D) { \
    float s0_ = __int_as_float(__builtin_amdgcn_update_dpp(one_i, __float_as_int(A.x), 0x110 | (D), 0xF, 0xF, false)); \
    float s1_ = __int_as_float(__builtin_amdgcn_update_dpp(one_i, __float_as_int(A.y), 0x110 | (D), 0xF, 0xF, false)); \
    A *= (f32x2){s0_, s1_}; }

// one 8-step scan body: consume ZC (local chunk offset T0L), prefetch ZN
// (T0L+8; last body over-prefetches into pad, never consumed), flush hx
// history for global steps T0G..T0G+7. Indices static after inlining.
__device__ __forceinline__ void scan_body8(
    int T0L, int T0G, const float* __restrict__ zrow,
    float* __restrict__ hlrow, bool writer,
    f32x4 (&ZC)[4], f32x4 (&ZN)[4],
    float& hx, float& cx,
    const f32x2 (&wp)[8], const f32x2 cth,
    const f32x2 k0, const f32x2 k1, const f32x2 k2, const f32x2 k3,
    const f32x2 k4, const int one_i)
{
    #pragma unroll
    for (int j = 0; j < 4; ++j)
        ZN[j] = *(const f32x4*)&zrow[(T0L + 8) * 2 + j * 4];

    float hxh[8];
    #pragma unroll
    for (int u = 0; u < 8; ++u) {
        const f32x2 z2 = (f32x2){ ZC[u >> 1][(u & 1) * 2],
                                  ZC[u >> 1][(u & 1) * 2 + 1] };

        // hx rotations (hx pair-duplicated; qubit shift s = lane ror 2s)
        const float h0 = hx;
        const float h1 = DPP_ROR(hx, 2),  h2 = DPP_ROR(hx, 4);
        const float h3 = DPP_ROR(hx, 6),  h4 = DPP_ROR(hx, 8);
        const float h5 = DPP_ROR(hx, 10), h6 = DPP_ROR(hx, 12);
        const float h7 = DPP_ROR(hx, 14);

        // pre-pair = z + hx @ Wh.T (balanced fma tree)
        f32x2 e0 = (f32x2){h0, h0} * wp[0] + (f32x2){h1, h1} * wp[1];
        f32x2 e1 = (f32x2){h2, h2} * wp[2] + (f32x2){h3, h3} * wp[3];
        f32x2 e2 = (f32x2){h4, h4} * wp[4] + (f32x2){h5, h5} * wp[5];
        f32x2 e3 = (f32x2){h6, h6} * wp[6] + (f32x2){h7, h7} * wp[7];
        const f32x2 p = ((z2 + e0) + (e1 + e2)) + e3;

        // qgate: a = cos(pre)*cos(theta), then qubit prefix product
        f32x2 A = (f32x2){__cosf(p.x), __cosf(p.y)} * cth;
        PSTG2(A, 2) PSTG2(A, 4) PSTG2(A, 8)

        // activations via per-lane poly (|A|<=1)
        const f32x2 t2 = A * A;
        f32x2 rr = k3 + t2 * k4;
        rr = k2 + t2 * rr;
        rr = k1 + t2 * rr;
        const f32x2 P = k0 + A * rr;

        // broadcast all 4 gates to both lanes of the pair (quad_perm)
        const float f_all = QP(P.x, 0xA0);   // [0,0,2,2]
        const float u_all = QP(P.x, 0xF5);   // [1,1,3,3]
        const float i_all = QP(P.y, 0xA0);
        const float o_all = QP(P.y, 0xF5);

        // cx = f*cx + i*u   (valid in ALL lanes, pair-duplicated)
        cx = fmaf(f_all, cx, i_all * u_all);

        // tanh(cx) via Pade[5/4] (|cx| <= ~2.1), 1 rcp
        const float tq  = cx * cx;
        const float num = cx * fmaf(tq, fmaf(tq, 1.0f, 105.0f), 945.0f);
        const float den = fmaf(tq, fmaf(tq, 15.0f, 420.0f), 945.0f);
        const float tc  = num * __builtin_amdgcn_rcpf(den);

        // hx = o * tanh(cx) — valid in all lanes
        hx = o_all * tc;
        hxh[u] = hx;
    }

    if (writer) {
        *(f32x4*)&hlrow[T0G]     = (f32x4){hxh[0], hxh[1], hxh[2], hxh[3]};
        *(f32x4*)&hlrow[T0G + 4] = (f32x4){hxh[4], hxh[5], hxh[6], hxh[7]};
    }
}

__global__ __launch_bounds__(512, 1) void qlstm_fused(
    const float* __restrict__ X,
    const float* __restrict__ Wf, const float* __restrict__ Wi,
    const float* __restrict__ Wu, const float* __restrict__ Wo,
    const float* __restrict__ bfv, const float* __restrict__ biv,
    const float* __restrict__ buv, const float* __restrict__ bov,
    const float* __restrict__ pf, const float* __restrict__ pi_,
    const float* __restrict__ pu, const float* __restrict__ po,
    float* __restrict__ out)
{
    // [nt(2)][hl(2)][ks(8)][lane(64)] bf16 B-fragments: 2048 * 16 B = 32 KB
    __shared__ short8 Wl[2048];
    // double-buffered Z chunk ring: [2][stream 0..31][t_local*2+comp]. 33 KB
    __shared__ float Zb[2][ZBUFSZ];
    // hx history: [c = bl*8+kq][t], stride 260. 16.25 KB
    __shared__ float Hl2[16 * HLSTR];

    const int tx  = threadIdx.x;
    const int l   = tx & 63;
    const int wid = tx >> 6;
    const int lm  = l & 15;
    const int lk  = l >> 4;
    const int B0  = blockIdx.x;              // batch pair index

    const float* Wg[4] = {Wf, Wi, Wu, Wo};
    const float* Bg[4] = {bfv, biv, buv, bov};

    // ---- preamble: convert W -> LDS bf16 hi/lo fragments (once per block) ---
    #pragma unroll
    for (int e = 0; e < 4; ++e) {
        const int ent  = tx + e * 512;       // 0..2047
        const int lane = ent & 63;
        const int ks   = (ent >> 6) & 7;
        const int hl   = (ent >> 9) & 1;
        const int nt   = (ent >> 10) & 1;
        const int elm  = lane & 15, elk = lane >> 4;
        const int c    = nt * 16 + elm;      // col = kq*4 + g
        const float* wrow = Wg[c & 3] + (c >> 2) * DCOMB + ks * 32 + elk * 8;
        short8 fr;
        #pragma unroll
        for (int j = 0; j < 8; ++j) {
            const float v = wrow[j];
            const short h16 = f2bf(v);
            fr[j] = hl ? f2bf(v - bf2f(h16)) : h16;
        }
        Wl[ent] = fr;
    }

    // bias per lane (bias of output col = lane's D column) — producers use
    float bias0, bias1;
    { const int c0 = lm;      bias0 = Bg[c0 & 3][c0 >> 2];
      const int c1 = 16 + lm; bias1 = Bg[c1 & 3][c1 >> 2]; }

    // ---- scanner state (wave 0 lanes only; cheap to set up) ----------------
    const int q   = tx & 15;                 // lane-in-batch 0..15
    const int kq  = q >> 1;                  // qubit index
    const int hi  = q & 1;                   // 0: gates (f,i); 1: (u,o)
    const int bl  = (tx >> 4) & 1;           // batch-in-pair (mirrored 32-63)
    const int oidx = (B0 * 2 + bl) * 8 + kq;
    const int woff = kq * DCOMB + DIN;

    f32x2 wp[8];
    f32x2 cth = (f32x2){1.0f, 1.0f};
    if (wid == 0) {
        const float* WgA = hi ? Wu : Wf;
        const float* WgB = hi ? Wo : Wi;
        #pragma unroll
        for (int s = 0; s < 8; ++s) {
            const int j = (kq - s) & 7;
            wp[s] = (f32x2){WgA[woff + j], WgB[woff + j]};
        }
        cth = (f32x2){__cosf((hi ? pu : pf)[kq]),
                      __cosf((hi ? po : pi_)[kq])};
    }
    // activation poly: act(x) = k0 + x*(k1 + t*(k2 + t*(k3 + t*k4))), t=x^2
    const float SK1 = 0.25f, SK2 = -0.0208333333f, SK3 = 0.0020833333f,
                SK4 = -0.00021082f;
    const f32x2 k0 = (f32x2){hi ? 0.0f : 0.5f, 0.5f};
    const f32x2 k1 = (f32x2){hi ? 0.9999016f : SK1, SK1};
    const f32x2 k2 = (f32x2){hi ? -0.3310485f : SK2, SK2};
    const f32x2 k3 = (f32x2){hi ? 0.1204423f : SK3, SK3};
    const f32x2 k4 = (f32x2){hi ? -0.0277012f : SK4, SK4};
    const int one_i = __float_as_int(1.0f);

    float hx = 0.0f, cx = 0.0f;
    const float* __restrict__ zrowb = &Zb[0][(bl * 16 + q) * ZBSTR];
    float* __restrict__ hlrow = &Hl2[(bl * 8 + kq) * HLSTR];
    const bool writer = (hi == 0) && (tx < 32);
    f32x4 zbA[4], zbB[4];

    __syncthreads();

    // ---- pipeline: 5 iterations; produce chunk k || scan chunk k-1 ---------
    // Producer slot map: wid {1,2,3,5} -> slot {0,1,2,3}. wid&3 = SIMD, so
    // SIMD0 hosts only the scan wave (wave 4 idles; SIMD1 gets 2 producers).
    const bool is_prod = (wid == 1) | (wid == 2) | (wid == 3) | (wid == 5);
    const int  slot    = wid - 1 - (wid > 4 ? 1 : 0);
    #pragma unroll 1
    for (int k = 0; k <= NCH; ++k) {
        if (wid == 0) {
            if (k >= 1) {
                // scan chunk k-1 (64 steps) from Zb[(k-1)&1]
                const float* __restrict__ zrow = zrowb + ((k - 1) & 1) * ZBUFSZ;
                const int TG = (k - 1) * CHT;
                #pragma unroll
                for (int j = 0; j < 4; ++j) zbA[j] = *(const f32x4*)&zrow[j * 4];
                scan_body8( 0, TG,      zrow, hlrow, writer, zbA, zbB, hx, cx, wp, cth, k0, k1, k2, k3, k4, one_i);
                scan_body8( 8, TG + 8,  zrow, hlrow, writer, zbB, zbA, hx, cx, wp, cth, k0, k1, k2, k3, k4, one_i);
                scan_body8(16, TG + 16, zrow, hlrow, writer, zbA, zbB, hx, cx, wp, cth, k0, k1, k2, k3, k4, one_i);
                scan_body8(24, TG + 24, zrow, hlrow, writer, zbB, zbA, hx, cx, wp, cth, k0, k1, k2, k3, k4, one_i);
                scan_body8(32, TG + 32, zrow, hlrow, writer, zbA, zbB, hx, cx, wp, cth, k0, k1, k2, k3, k4, one_i);
                scan_body8(40, TG + 40, zrow, hlrow, writer, zbB, zbA, hx, cx, wp, cth, k0, k1, k2, k3, k4, one_i);
                scan_body8(48, TG + 48, zrow, hlrow, writer, zbA, zbB, hx, cx, wp, cth, k0, k1, k2, k3, k4, one_i);
                scan_body8(56, TG + 56, zrow, hlrow, writer, zbB, zbA, hx, cx, wp, cth, k0, k1, k2, k3, k4, one_i);
                if (k == NCH && writer) {
                    out[NROWS * 8 + oidx]        = hx;   // final hx (512,8)
                    out[NROWS * 8 + 4096 + oidx] = cx;   // final cx (512,8)
                }
            }
        } else if (is_prod && k < NCH) {
            // produce chunk k (128 local rows) into Zb[k&1]
            float* __restrict__ bufp = &Zb[k & 1][0];
            #pragma unroll
            for (int g = 0; g < 2; ++g) {
                const int r0 = k * 128 + slot * 32 + g * 16;
                const int r  = r0 + lm;      // this lane's A-row (= 2t+bl local)
                const float* xbase =
                    X + ((long)(r >> 1) * BATCH + B0 * 2 + (r & 1)) * DIN + lk * 8;

                float4 xv[16];
                #pragma unroll
                for (int i = 0; i < 16; ++i)
                    xv[i] = *(const float4*)(xbase + (i >> 1) * 32 + (i & 1) * 4);

                f32x4 acc0 = (f32x4){bias0, bias0, bias0, bias0};
                f32x4 acc1 = (f32x4){bias1, bias1, bias1, bias1};
                #pragma unroll
                for (int ks = 0; ks < 8; ++ks) {
                    const short8 a = pack8(xv[2 * ks], xv[2 * ks + 1]);
                    acc0 = __builtin_amdgcn_mfma_f32_16x16x32_bf16(a, Wl[ks * 64 + l],        acc0, 0, 0, 0);
                    acc0 = __builtin_amdgcn_mfma_f32_16x16x32_bf16(a, Wl[(8  + ks) * 64 + l], acc0, 0, 0, 0);
                    acc1 = __builtin_amdgcn_mfma_f32_16x16x32_bf16(a, Wl[(16 + ks) * 64 + l], acc1, 0, 0, 0);
                    acc1 = __builtin_amdgcn_mfma_f32_16x16x32_bf16(a, Wl[(24 + ks) * 64 + l], acc1, 0, 0, 0);
                }

                // D layout: col = lane&15, row = (lane>>4)*4 + reg.
                // (local r, col c) -> stream (r&1)*16 + (c>>1), idx tl*2+(c&1)
                #pragma unroll
                for (int rr = 0; rr < 4; ++rr) {
                    const int rw   = r0 + lk * 4 + rr;
                    const int tl   = (rw - k * 128) >> 1;
                    const int blw  = rw & 1;
                    bufp[(blw * 16 + (lm >> 1)) * ZBSTR + tl * 2 + (lm & 1)]     = acc0[rr];
                    bufp[(blw * 16 + 8 + (lm >> 1)) * ZBSTR + tl * 2 + (lm & 1)] = acc1[rr];
                }
            }
        }
        __syncthreads();
    }

    // ---- epilogue: gather-transpose dump of hx history (all 8 waves) -------
    {
        const int f0 = tx * 8;               // 0..4095
        const int t  = f0 >> 4;              // 0..255
        const int c0 = f0 & 15;              // 0 or 8
        float4 v0, v1;
        v0.x = Hl2[(c0 + 0) * HLSTR + t];
        v0.y = Hl2[(c0 + 1) * HLSTR + t];
        v0.z = Hl2[(c0 + 2) * HLSTR + t];
        v0.w = Hl2[(c0 + 3) * HLSTR + t];
        v1.x = Hl2[(c0 + 4) * HLSTR + t];
        v1.y = Hl2[(c0 + 5) * HLSTR + t];
        v1.z = Hl2[(c0 + 6) * HLSTR + t];
        v1.w = Hl2[(c0 + 7) * HLSTR + t];
        float4* dst = (float4*)(out + (long)t * (BATCH * 8) + B0 * 16 + c0);
        dst[0] = v0;
        dst[1] = v1;
    }
}

// ---------------------------------------------------------------------------
extern "C" void kernel_launch(void* const* d_in, const int* in_sizes, int n_in,
                              void* d_out, int out_size, void* d_ws, size_t ws_size,
                              hipStream_t stream) {
    const float* X   = (const float*)d_in[0];
    const float* Wf  = (const float*)d_in[1];
    const float* bfv = (const float*)d_in[2];
    const float* Wi  = (const float*)d_in[3];
    const float* biv = (const float*)d_in[4];
    const float* Wu  = (const float*)d_in[5];
    const float* buv = (const float*)d_in[6];
    const float* Wo  = (const float*)d_in[7];
    const float* bov = (const float*)d_in[8];
    const float* pf  = (const float*)d_in[9];
    const float* pi_ = (const float*)d_in[10];
    const float* pu  = (const float*)d_in[11];
    const float* po  = (const float*)d_in[12];
    float* out = (float*)d_out;
    (void)d_ws; (void)ws_size;               // workspace not needed

    qlstm_fused<<<BATCH / 2, 512, 0, stream>>>(
        X, Wf, Wi, Wu, Wo, bfv, biv, buv, bov, pf, pi_, pu, po, out);
}